// Round 3
// baseline (153.396 us; speedup 1.0000x reference)
//
#include <hip/hip_runtime.h>

#define ROI 31
#define HALF 15
#define H_DIM 256
#define W_DIM 256
#define C_DIM 32
#define NBUCKET 1024   // b(16) x (y>>5)(8) x (x>>5)(8)

typedef float vfloat4 __attribute__((ext_vector_type(4)));

// Single-block counting sort of ROI indices by spatial bucket.
// perm[pos] = original roi index, ordered by (b, y/32, x/32).
__global__ __launch_bounds__(1024) void roi_sort_kernel(
    const int* __restrict__ centers, int* __restrict__ perm, int N)
{
    __shared__ int hist[NBUCKET];
    __shared__ int scan[NBUCKET];
    __shared__ int base[NBUCKET];
    const int t = threadIdx.x;

    hist[t] = 0;
    __syncthreads();

    for (int i = t; i < N; i += 1024) {
        const int b = centers[3 * i + 0];
        const int y = centers[3 * i + 1];
        const int x = centers[3 * i + 2];
        const int key = (b << 6) | ((y >> 5) << 3) | (x >> 5);
        atomicAdd(&hist[key], 1);
    }
    __syncthreads();

    // Hillis-Steele inclusive scan over 1024 buckets
    scan[t] = hist[t];
    __syncthreads();
    for (int off = 1; off < NBUCKET; off <<= 1) {
        int v = (t >= off) ? scan[t - off] : 0;
        __syncthreads();
        scan[t] += v;
        __syncthreads();
    }
    base[t] = scan[t] - hist[t];   // exclusive
    hist[t] = 0;                   // reuse as per-bucket cursor
    __syncthreads();

    for (int i = t; i < N; i += 1024) {
        const int b = centers[3 * i + 0];
        const int y = centers[3 * i + 1];
        const int x = centers[3 * i + 2];
        const int key = (b << 6) | ((y >> 5) << 3) | (x >> 5);
        const int pos = base[key] + atomicAdd(&hist[key], 1);
        perm[pos] = i;
    }
}

__global__ __launch_bounds__(256) void roi_extract_kernel(
    const float* __restrict__ poses,   // [B,256,256,32]
    const int*   __restrict__ centers, // [N,3] (b,y,x)
    const int*   __restrict__ perm,    // [N] sorted roi order
    float*       __restrict__ out)     // [N,31,31,32]
{
    const int n = perm[blockIdx.x];    // spatially-clustered processing order
    const int t = threadIdx.x;         // 0..255

    const int b = centers[n * 3 + 0];
    const int y = centers[n * 3 + 1];
    const int x = centers[n * 3 + 2];

    if (t >= ROI * (C_DIM / 4)) return;   // 248 active threads
    const int c = t >> 3;                 // ROI col 0..30
    const int q = t & 7;                  // float4 index within pixel

    const int cc   = x + c - HALF;
    const bool cok = (cc >= 0) && (cc < W_DIM);
    const int ccc  = min(max(cc, 0), W_DIM - 1);

    const vfloat4* src = reinterpret_cast<const vfloat4*>(
        poses + ((size_t)b * H_DIM * W_DIM + ccc) * C_DIM) + q;
    vfloat4* dst = reinterpret_cast<vfloat4*>(
        out + ((size_t)n * ROI * ROI + c) * C_DIM) + q;

    const int r0 = y - HALF;
    const size_t src_row_stride = (size_t)W_DIM * (C_DIM / 4);
    const size_t dst_row_stride = (size_t)ROI * (C_DIM / 4);

    #pragma unroll
    for (int r = 0; r < ROI; ++r) {
        const int rr = r0 + r;
        const bool ok = cok && (rr >= 0) && (rr < H_DIM);
        vfloat4 v = (vfloat4)0.0f;
        if (ok) {
            v = src[(size_t)rr * src_row_stride];
        }
        // stream output past caches; keep L2/L3 for the input
        __builtin_nontemporal_store(v, dst + (size_t)r * dst_row_stride);
    }
}

extern "C" void kernel_launch(void* const* d_in, const int* in_sizes, int n_in,
                              void* d_out, int out_size, void* d_ws, size_t ws_size,
                              hipStream_t stream) {
    const float* poses   = (const float*)d_in[0];
    const int*   centers = (const int*)d_in[1];
    float*       out     = (float*)d_out;
    int*         perm    = (int*)d_ws;       // N ints of scratch

    const int N = in_sizes[1] / 3;

    roi_sort_kernel<<<dim3(1), dim3(1024), 0, stream>>>(centers, perm, N);
    roi_extract_kernel<<<dim3(N), dim3(256), 0, stream>>>(poses, centers, perm, out);
}

// Round 4
// 152.107 us; speedup vs baseline: 1.0085x; 1.0085x over previous
//
#include <hip/hip_runtime.h>

#define ROI 31
#define HALF 15
#define H_DIM 256
#define W_DIM 256
#define C_DIM 32
#define NBUCKET 1024   // b(16) x (y>>5)(8) x (x>>5)(8)
#define GRID 1024      // persistent blocks; co-resident locality window

typedef float vfloat4 __attribute__((ext_vector_type(4)));

// Single-block counting sort of ROI indices by spatial bucket.
__global__ __launch_bounds__(1024) void roi_sort_kernel(
    const int* __restrict__ centers, int* __restrict__ perm, int N)
{
    __shared__ int hist[NBUCKET];
    __shared__ int scan[NBUCKET];
    __shared__ int base[NBUCKET];
    const int t = threadIdx.x;

    hist[t] = 0;
    __syncthreads();

    for (int i = t; i < N; i += 1024) {
        const int b = centers[3 * i + 0];
        const int y = centers[3 * i + 1];
        const int x = centers[3 * i + 2];
        const int key = (b << 6) | ((y >> 5) << 3) | (x >> 5);
        atomicAdd(&hist[key], 1);
    }
    __syncthreads();

    scan[t] = hist[t];
    __syncthreads();
    for (int off = 1; off < NBUCKET; off <<= 1) {
        int v = (t >= off) ? scan[t - off] : 0;
        __syncthreads();
        scan[t] += v;
        __syncthreads();
    }
    base[t] = scan[t] - hist[t];   // exclusive
    hist[t] = 0;                   // per-bucket cursor
    __syncthreads();

    for (int i = t; i < N; i += 1024) {
        const int b = centers[3 * i + 0];
        const int y = centers[3 * i + 1];
        const int x = centers[3 * i + 2];
        const int key = (b << 6) | ((y >> 5) << 3) | (x >> 5);
        const int pos = base[key] + atomicAdd(&hist[key], 1);
        perm[pos] = i;
    }
}

// Persistent grid: block g handles sorted positions {k*GRID + g}.
// At step k all co-resident blocks share a contiguous sorted window of
// GRID ROIs (~32 MB unique input) -> L3-resident reads.
__global__ __launch_bounds__(256) void roi_extract_kernel(
    const float* __restrict__ poses,
    const int*   __restrict__ centers,
    const int*   __restrict__ perm,
    float*       __restrict__ out,
    int N, int nper)
{
    const int t = threadIdx.x;
    if (t >= ROI * (C_DIM / 4)) return;   // 248 active
    const int c = t >> 3;                 // ROI col 0..30
    const int q = t & 7;                  // float4 index within pixel

    const size_t src_row_stride = (size_t)W_DIM * (C_DIM / 4);
    const size_t dst_row_stride = (size_t)ROI * (C_DIM / 4);

    for (int k = 0; k < nper; ++k) {
        const int pos = k * GRID + blockIdx.x;   // sliding sorted window
        if (pos >= N) return;
        const int n = perm[pos];                 // uniform -> scalar load

        const int b = centers[n * 3 + 0];
        const int y = centers[n * 3 + 1];
        const int x = centers[n * 3 + 2];

        const int cc   = x + c - HALF;
        const bool cok = (cc >= 0) && (cc < W_DIM);
        const int ccc  = min(max(cc, 0), W_DIM - 1);

        const vfloat4* src = reinterpret_cast<const vfloat4*>(
            poses + ((size_t)b * H_DIM * W_DIM + ccc) * C_DIM) + q;
        vfloat4* dst = reinterpret_cast<vfloat4*>(
            out + ((size_t)n * ROI * ROI + c) * C_DIM) + q;

        const int r0 = y - HALF;

        #pragma unroll
        for (int r = 0; r < ROI; ++r) {
            const int rr = r0 + r;
            const bool ok = cok && (rr >= 0) && (rr < H_DIM);
            vfloat4 v = (vfloat4)0.0f;
            if (ok) {
                v = src[(size_t)rr * src_row_stride];
            }
            // stream output past caches; keep L3 for the input
            __builtin_nontemporal_store(v, dst + (size_t)r * dst_row_stride);
        }
    }
}

extern "C" void kernel_launch(void* const* d_in, const int* in_sizes, int n_in,
                              void* d_out, int out_size, void* d_ws, size_t ws_size,
                              hipStream_t stream) {
    const float* poses   = (const float*)d_in[0];
    const int*   centers = (const int*)d_in[1];
    float*       out     = (float*)d_out;
    int*         perm    = (int*)d_ws;

    const int N = in_sizes[1] / 3;
    const int nper = (N + GRID - 1) / GRID;

    roi_sort_kernel<<<dim3(1), dim3(1024), 0, stream>>>(centers, perm, N);
    roi_extract_kernel<<<dim3(GRID), dim3(256), 0, stream>>>(poses, centers, perm, out, N, nper);
}